// Round 14
// baseline (249.574 us; speedup 1.0000x reference)
//
#include <hip/hip_runtime.h>

#define K_IN   256
#define N_OUT  128
#define BM     32
#define SCAN_CHUNK 1024
#define NBLK   512        // hist/scatter partition width
#define BSHIFT 7
#define BNODES 128        // dst nodes per bucket
#define CAP    8192       // record capacity of LDS sort buffer (64 KB)
#define NKEY   2048       // sort bins: (dstLow<<4) | (src>>13)
#define NXCD   8

typedef short bf16x8 __attribute__((ext_vector_type(8)));
typedef float f32x4  __attribute__((ext_vector_type(4)));

static __device__ __forceinline__ unsigned short f2bf(float f) {
    unsigned u = __float_as_uint(f);
    unsigned r = (u + 0x7FFF + ((u >> 16) & 1)) >> 16;   // RNE
    return (unsigned short)r;
}
static __device__ __forceinline__ float bf2f(unsigned short b) {
    return __uint_as_float(((unsigned)b) << 16);
}

// ---- K1: blocks 0..NBLK-1 = dst histogram; blocks NBLK.. = W prep ----
__global__ __launch_bounds__(256) void hist_prep(
    const float* __restrict__ W, char* __restrict__ wbt,
    const int* __restrict__ ei, int* __restrict__ histG,
    int M, int E, int B, int chunk)
{
    __shared__ int bins[1024];
    const int tid = threadIdx.x;

    if (blockIdx.x >= NBLK) {
        const int t = (blockIdx.x - NBLK) * 256 + tid;
        if (t >= N_OUT * 32) return;
        const int n = t >> 5;
        const int c = t & 31;
        unsigned v[4];
#pragma unroll
        for (int p = 0; p < 4; ++p) {
            const unsigned lo = f2bf(W[(size_t)(c * 8 + 2 * p)     * N_OUT + n]);
            const unsigned hi = f2bf(W[(size_t)(c * 8 + 2 * p + 1) * N_OUT + n]);
            v[p] = lo | (hi << 16);
        }
        const int byte = n * 512 + ((c * 16) ^ ((n & 7) << 4));
        *reinterpret_cast<uint4*>(wbt + byte) = make_uint4(v[0], v[1], v[2], v[3]);
        return;
    }

    for (int i = tid; i < B; i += 256) bins[i] = 0;
    __syncthreads();
    const int beg = blockIdx.x * chunk;
    const int end = min(beg + chunk, E);
    for (int i = beg + tid; i < end; i += 256)
        atomicAdd(&bins[ei[i] >> BSHIFT], 1);
    __syncthreads();
    for (int i = tid; i < B; i += 256) histG[i * NBLK + blockIdx.x] = bins[i];
}

// ---- scans over n = B*NBLK entries ----
__global__ __launch_bounds__(256) void scan_block_sums(
    const int* __restrict__ cnt, int n, int* __restrict__ bsum)
{
    __shared__ int sd[256];
    const int base = blockIdx.x * SCAN_CHUNK + threadIdx.x * 4;
    int s = 0;
#pragma unroll
    for (int j = 0; j < 4; ++j) { const int idx = base + j; if (idx < n) s += cnt[idx]; }
    sd[threadIdx.x] = s; __syncthreads();
    for (int off = 128; off > 0; off >>= 1) {
        if (threadIdx.x < off) sd[threadIdx.x] += sd[threadIdx.x + off];
        __syncthreads();
    }
    if (threadIdx.x == 0) bsum[blockIdx.x] = sd[0];
}

__global__ __launch_bounds__(1024) void scan_sums(
    int* __restrict__ bsum, int nb, int* __restrict__ P, int n)
{
    __shared__ int sd[1024];
    const int t = threadIdx.x;
    const int v = (t < nb) ? bsum[t] : 0;
    sd[t] = v; __syncthreads();
    for (int off = 1; off < 1024; off <<= 1) {
        const int add = (t >= off) ? sd[t - off] : 0;
        __syncthreads();
        sd[t] += add;
        __syncthreads();
    }
    if (t < nb) bsum[t] = sd[t] - v;
    if (t == nb - 1) P[n] = sd[t];
}

__global__ __launch_bounds__(256) void scan_write_offsets(
    const int* __restrict__ cnt, int n, const int* __restrict__ bsum, int* __restrict__ P)
{
    __shared__ int sd[256];
    const int t = threadIdx.x;
    const int base = blockIdx.x * SCAN_CHUNK + t * 4;
    int v[4]; int s = 0;
#pragma unroll
    for (int j = 0; j < 4; ++j) { const int idx = base + j; v[j] = (idx < n) ? cnt[idx] : 0; s += v[j]; }
    sd[t] = s; __syncthreads();
    const int own = s;
    for (int off = 1; off < 256; off <<= 1) {
        const int add = (t >= off) ? sd[t - off] : 0;
        __syncthreads();
        sd[t] += add;
        __syncthreads();
    }
    int run = bsum[blockIdx.x] + (sd[t] - own);
#pragma unroll
    for (int j = 0; j < 4; ++j) {
        const int idx = base + j;
        if (idx < n) { P[idx] = run; run += v[j]; }
    }
}

// ---- Merged persistent-W GEMM (even blocks) + scatter_records (odd blocks).
// 1024 blocks, 80KB LDS -> exactly 1 gemm + 1 scatter block per CU:
// scatter's memory phase hides under GEMM's MFMA/staging compute.
__global__ __launch_bounds__(256) void gemm_scatter2(
    const float* __restrict__ x, const uint4* __restrict__ wbt,
    const float* __restrict__ bias, unsigned short* __restrict__ hb,
    const int* __restrict__ ei, const float* __restrict__ ew,
    const int* __restrict__ P, uint2* __restrict__ rec,
    int M, int E, int B, int chunk, int ntiles)
{
    __shared__ uint4 smem4[81920 / 16];
    char* smem = (char*)smem4;
    const int tid = threadIdx.x;

    if (blockIdx.x & 1) {
        // ---- scatter role ----
        int* cur = (int*)smem;
        const int blk = blockIdx.x >> 1;        // 0..NBLK-1
        for (int i = tid; i < B; i += 256) cur[i] = P[i * NBLK + blk];
        __syncthreads();
        const int beg = blk * chunk;
        const int end = min(beg + chunk, E);
        for (int i = beg + tid; i < end; i += 256) {
            const int d = ei[i];
            const int s = ei[(size_t)E + i];
            const int pos = atomicAdd(&cur[d >> BSHIFT], 1);
            rec[pos] = make_uint2((unsigned)s | ((unsigned)(d & (BNODES - 1)) << 24),
                                  __float_as_uint(ew[i]));
        }
        return;
    }

    // ---- persistent-W GEMM role ----
    const int gemm_id = blockIdx.x >> 1;        // 0..511
    const int gstride = gridDim.x >> 1;         // 512

    {
        uint4* wl = (uint4*)smem;
#pragma unroll
        for (int it = 0; it < 16; ++it) wl[it * 256 + tid] = wbt[it * 256 + tid];
    }

    const int lane = tid & 63;
    const int wv   = tid >> 6;
    const int wr   = wv >> 1;
    const int wc   = wv & 1;
    const int l15  = lane & 15;
    const int lk   = lane >> 4;

    const int  arow = wr * 16 + l15;
    const char* xrow = smem + 65536 + arow * 512;
    const int  aswz = (arow & 7) << 4;
    const int  bswz = (l15 & 7) << 4;
    const char* brow0 = smem + (size_t)(wc * 64 + l15) * 512;

    float bv[4];
#pragma unroll
    for (int j = 0; j < 4; ++j) bv[j] = bias[wc * 64 + j * 16 + l15];

    const int sr  = tid >> 3;
    const int sks = tid & 7;
    char* xbase   = smem + 65536 + sr * 512;
    const int swz = (sr & 7) << 4;

    for (int t = gemm_id; t < ntiles; t += gstride) {
        const int row0 = t * BM;

        __syncthreads();
        {
            const int grow = row0 + sr;
            if (grow < M) {
                const float4* src = reinterpret_cast<const float4*>(x + (size_t)grow * K_IN + sks * 32);
#pragma unroll
                for (int q = 0; q < 8; ++q) {
                    const float4 f = src[q];
                    uint2 v;
                    v.x = (unsigned)f2bf(f.x) | ((unsigned)f2bf(f.y) << 16);
                    v.y = (unsigned)f2bf(f.z) | ((unsigned)f2bf(f.w) << 16);
                    const int kb = sks * 64 + q * 8;
                    *reinterpret_cast<uint2*>(xbase + (((kb & ~15) ^ swz) | (kb & 15))) = v;
                }
            } else {
                const uint2 z = make_uint2(0u, 0u);
#pragma unroll
                for (int q = 0; q < 8; ++q) {
                    const int kb = sks * 64 + q * 8;
                    *reinterpret_cast<uint2*>(xbase + (((kb & ~15) ^ swz) | (kb & 15))) = z;
                }
            }
        }
        __syncthreads();

        f32x4 acc[4] = {};
#pragma unroll
        for (int ks = 0; ks < 8; ++ks) {
            const int kb = ks * 64 + lk * 16;
            const bf16x8 a = *reinterpret_cast<const bf16x8*>(xrow + (kb ^ aswz));
            const int bk = kb ^ bswz;
#pragma unroll
            for (int j = 0; j < 4; ++j) {
                const bf16x8 b = *reinterpret_cast<const bf16x8*>(brow0 + j * (16 * 512) + bk);
                acc[j] = __builtin_amdgcn_mfma_f32_16x16x32_bf16(a, b, acc[j], 0, 0, 0);
            }
        }

#pragma unroll
        for (int j = 0; j < 4; ++j) {
            const int gcol = wc * 64 + j * 16 + l15;
#pragma unroll
            for (int r = 0; r < 4; ++r) {
                const int grow = row0 + wr * 16 + lk * 4 + r;
                if (grow < M)
                    hb[(size_t)grow * N_OUT + gcol] = f2bf(acc[j][r] + bv[j]);
            }
        }
    }
}

// ---- Pass C: per-bucket in-place counting sort by (dstLow, srcWindow) key
__global__ __launch_bounds__(256) void sort_bucket(
    const int* __restrict__ P, uint2* __restrict__ rec,
    int* __restrict__ offsN, int* __restrict__ bflag, int M, int B)
{
    __shared__ uint2 srt[CAP];          // 64 KB staging
    __shared__ int hist[NKEY];          // 8 KB
    __shared__ int sd[256];

    const int b   = blockIdx.x;
    const int tid = threadIdx.x;
    const int beg = P[b * NBLK];
    const int end = P[(b + 1) * NBLK];
    const int cnt = end - beg;
    const int node0 = b << BSHIFT;

    for (int i = tid; i < NKEY; i += 256) hist[i] = 0;
    if (tid == 0) bflag[b] = (cnt <= CAP) ? 0 : 1;
    if (tid == 0 && b == B - 1) offsN[M] = end;
    __syncthreads();

    if (cnt > CAP) {
        if (tid < BNODES) {
            const int node = node0 + tid;
            if (node < M) offsN[node] = beg;
        }
        return;
    }

    for (int i = beg + tid; i < end; i += 256) {
        const uint2 r = rec[i];
        srt[i - beg] = r;
        const int key = ((r.x >> 24) << 4) | ((r.x & 0xFFFFFF) >> 13);
        atomicAdd(&hist[key], 1);
    }
    __syncthreads();

    const int base = tid * 8;
    int v[8]; int s = 0;
#pragma unroll
    for (int j = 0; j < 8; ++j) { v[j] = hist[base + j]; s += v[j]; }
    sd[tid] = s; __syncthreads();
    for (int off = 1; off < 256; off <<= 1) {
        const int add = (tid >= off) ? sd[tid - off] : 0;
        __syncthreads();
        sd[tid] += add;
        __syncthreads();
    }
    int run = sd[tid] - s;
#pragma unroll
    for (int j = 0; j < 8; ++j) { hist[base + j] = run; run += v[j]; }
    __syncthreads();

    if (tid < BNODES) {
        const int node = node0 + tid;
        if (node < M) offsN[node] = beg + hist[tid << 4];
    }
    __syncthreads();

    for (int i = tid; i < cnt; i += 256) {
        const uint2 r = srt[i];
        const int key = ((r.x >> 24) << 4) | ((r.x & 0xFFFFFF) >> 13);
        const int pos = atomicAdd(&hist[key], 1);
        rec[beg + pos] = r;
    }
}

// ---- Gather: one wave per node; XCD-swizzled blockIdx so each XCD owns a
// contiguous bucket range -> co-resident waves sweep the same src windows
// (the round-6 window sort order) through the same L2.
__global__ __launch_bounds__(256) void gather_kernel(
    const int* __restrict__ offsN, const int* __restrict__ P,
    const int* __restrict__ bflag, const uint2* __restrict__ rec,
    const unsigned short* __restrict__ hb, float* __restrict__ out, int M)
{
    // bijective chunked XCD swizzle (m204 form)
    const int nwg = gridDim.x;
    const int q   = nwg / NXCD;
    const int r   = nwg % NXCD;
    const int xcd = blockIdx.x % NXCD;
    const int idx = blockIdx.x / NXCD;
    const int swz = (xcd < r ? xcd * (q + 1) : r * (q + 1) + (xcd - r) * q) + idx;

    const int n = swz * 4 + (threadIdx.x >> 6);
    if (n >= M) return;
    const int lane = threadIdx.x & 63;
    const int b = n >> BSHIFT;
    const unsigned* __restrict__ hb32 = reinterpret_cast<const unsigned*>(hb);

    float ax = 0.f, ay = 0.f;

    if (bflag[b] == 0) {
        const int beg = offsN[n], end = offsN[n + 1];
        int i = beg;
        for (; i + 16 <= end; i += 16) {
            unsigned u[16]; float w[16];
#pragma unroll
            for (int qq = 0; qq < 16; ++qq) {
                const uint2 rr = rec[i + qq];
                w[qq] = __uint_as_float(rr.y);
                u[qq] = hb32[(size_t)((rr.x & 0xFFFFFF) << 6) + lane];
            }
#pragma unroll
            for (int qq = 0; qq < 16; ++qq) {
                ax += w[qq] * bf2f((unsigned short)u[qq]);
                ay += w[qq] * bf2f((unsigned short)(u[qq] >> 16));
            }
        }
        for (; i + 8 <= end; i += 8) {
            unsigned u[8]; float w[8];
#pragma unroll
            for (int qq = 0; qq < 8; ++qq) {
                const uint2 rr = rec[i + qq];
                w[qq] = __uint_as_float(rr.y);
                u[qq] = hb32[(size_t)((rr.x & 0xFFFFFF) << 6) + lane];
            }
#pragma unroll
            for (int qq = 0; qq < 8; ++qq) {
                ax += w[qq] * bf2f((unsigned short)u[qq]);
                ay += w[qq] * bf2f((unsigned short)(u[qq] >> 16));
            }
        }
        for (; i < end; ++i) {
            const uint2 rr = rec[i];
            const float w = __uint_as_float(rr.y);
            const unsigned u = hb32[(size_t)((rr.x & 0xFFFFFF) << 6) + lane];
            ax += w * bf2f((unsigned short)u);
            ay += w * bf2f((unsigned short)(u >> 16));
        }
    } else {
        const int beg = P[b * NBLK], end = P[(b + 1) * NBLK];
        const unsigned want = (unsigned)(n & (BNODES - 1));
        for (int i = beg; i < end; ++i) {
            const uint2 rr = rec[i];
            if ((rr.x >> 24) != want) continue;
            const float w = __uint_as_float(rr.y);
            const unsigned u = hb32[(size_t)((rr.x & 0xFFFFFF) << 6) + lane];
            ax += w * bf2f((unsigned short)u);
            ay += w * bf2f((unsigned short)(u >> 16));
        }
    }

    reinterpret_cast<float2*>(out + (size_t)n * N_OUT)[lane] = make_float2(ax, ay);
}

extern "C" void kernel_launch(void* const* d_in, const int* in_sizes, int n_in,
                              void* d_out, int out_size, void* d_ws, size_t ws_size,
                              hipStream_t stream)
{
    const float* x    = (const float*)d_in[0];
    const int*   ei   = (const int*)d_in[1];
    const float* ew   = (const float*)d_in[2];
    const float* W    = (const float*)d_in[3];
    const float* bias = (const float*)d_in[4];
    float* out = (float*)d_out;

    const int M = in_sizes[0] / K_IN;   // 100000
    const int E = in_sizes[1] / 2;      // 3200000
    const int B = (M + BNODES - 1) >> BSHIFT;          // 782
    const int n = B * NBLK;                             // 400384
    const int nb = (n + SCAN_CHUNK - 1) / SCAN_CHUNK;   // 391
    const int chunk = (E + NBLK - 1) / NBLK;            // 6250
    const int ntiles = (M + BM - 1) / BM;               // 3125

    auto align256 = [](size_t v) { return (v + 255) & ~(size_t)255; };
    const size_t o_hb    = 0;
    const size_t o_hist  = align256(o_hb + (size_t)M * N_OUT * sizeof(unsigned short));
    const size_t o_P     = align256(o_hist + (size_t)n * sizeof(int));
    const size_t o_bsum  = align256(o_P + (size_t)(n + 1) * sizeof(int));
    const size_t o_offsN = align256(o_bsum + (size_t)1024 * sizeof(int));
    const size_t o_bflag = align256(o_offsN + (size_t)(M + 1) * sizeof(int));
    const size_t o_wbt   = align256(o_bflag + (size_t)B * sizeof(int));
    const size_t o_rec   = align256(o_wbt + (size_t)65536);

    unsigned short* hb    = (unsigned short*)((char*)d_ws + o_hb);
    int*            histG = (int*)((char*)d_ws + o_hist);
    int*            P     = (int*)((char*)d_ws + o_P);
    int*            bsum  = (int*)((char*)d_ws + o_bsum);
    int*            offsN = (int*)((char*)d_ws + o_offsN);
    int*            bflag = (int*)((char*)d_ws + o_bflag);
    char*           wbt   = (char*)d_ws + o_wbt;
    uint2*          rec   = (uint2*)((char*)d_ws + o_rec);

    hist_prep<<<NBLK + 16, 256, 0, stream>>>(W, wbt, ei, histG, M, E, B, chunk);
    scan_block_sums<<<nb, 256, 0, stream>>>(histG, n, bsum);
    scan_sums<<<1, 1024, 0, stream>>>(bsum, nb, P, n);
    scan_write_offsets<<<nb, 256, 0, stream>>>(histG, n, bsum, P);
    gemm_scatter2<<<2 * NBLK, 256, 0, stream>>>(
        x, (const uint4*)wbt, bias, hb, ei, ew, P, rec, M, E, B, chunk, ntiles);
    sort_bucket<<<B, 256, 0, stream>>>(P, rec, offsN, bflag, M, B);
    gather_kernel<<<(M + 3) / 4, 256, 0, stream>>>(offsN, P, bflag, rec, hb, out, M);
}

// Round 15
// 240.569 us; speedup vs baseline: 1.0374x; 1.0374x over previous
//
#include <hip/hip_runtime.h>

#define K_IN   256
#define N_OUT  128
#define BM     32
#define SCAN_CHUNK 1024
#define NBLK   512        // hist/scatter partition width
#define BSHIFT 7
#define BNODES 128        // dst nodes per bucket
#define CAP    8192       // record capacity of LDS sort buffer (64 KB)
#define NKEY   2048       // sort bins: (dstLow<<4) | (src>>13)
#define GEMM_BLOCKS 512   // persistent-W GEMM grid

typedef short bf16x8 __attribute__((ext_vector_type(8)));
typedef float f32x4  __attribute__((ext_vector_type(4)));

static __device__ __forceinline__ unsigned short f2bf(float f) {
    unsigned u = __float_as_uint(f);
    unsigned r = (u + 0x7FFF + ((u >> 16) & 1)) >> 16;   // RNE
    return (unsigned short)r;
}
static __device__ __forceinline__ float bf2f(unsigned short b) {
    return __uint_as_float(((unsigned)b) << 16);
}

// ---- K1: blocks 0..NBLK-1 = dst histogram; blocks NBLK.. = W prep ----
__global__ __launch_bounds__(256) void hist_prep(
    const float* __restrict__ W, char* __restrict__ wbt,
    const int* __restrict__ ei, int* __restrict__ histG,
    int M, int E, int B, int chunk)
{
    __shared__ int bins[1024];
    const int tid = threadIdx.x;

    if (blockIdx.x >= NBLK) {
        // prep_w role: W[256][128] fp32 -> pre-swizzled bf16 image (64KB)
        const int t = (blockIdx.x - NBLK) * 256 + tid;
        if (t >= N_OUT * 32) return;
        const int n = t >> 5;
        const int c = t & 31;
        unsigned v[4];
#pragma unroll
        for (int p = 0; p < 4; ++p) {
            const unsigned lo = f2bf(W[(size_t)(c * 8 + 2 * p)     * N_OUT + n]);
            const unsigned hi = f2bf(W[(size_t)(c * 8 + 2 * p + 1) * N_OUT + n]);
            v[p] = lo | (hi << 16);
        }
        const int byte = n * 512 + ((c * 16) ^ ((n & 7) << 4));
        *reinterpret_cast<uint4*>(wbt + byte) = make_uint4(v[0], v[1], v[2], v[3]);
        return;
    }

    // histogram role
    for (int i = tid; i < B; i += 256) bins[i] = 0;
    __syncthreads();
    const int beg = blockIdx.x * chunk;
    const int end = min(beg + chunk, E);
    for (int i = beg + tid; i < end; i += 256)
        atomicAdd(&bins[ei[i] >> BSHIFT], 1);
    __syncthreads();
    for (int i = tid; i < B; i += 256) histG[i * NBLK + blockIdx.x] = bins[i];
}

// ---- scans over n = B*NBLK entries ----
__global__ __launch_bounds__(256) void scan_block_sums(
    const int* __restrict__ cnt, int n, int* __restrict__ bsum)
{
    __shared__ int sd[256];
    const int base = blockIdx.x * SCAN_CHUNK + threadIdx.x * 4;
    int s = 0;
#pragma unroll
    for (int j = 0; j < 4; ++j) { const int idx = base + j; if (idx < n) s += cnt[idx]; }
    sd[threadIdx.x] = s; __syncthreads();
    for (int off = 128; off > 0; off >>= 1) {
        if (threadIdx.x < off) sd[threadIdx.x] += sd[threadIdx.x + off];
        __syncthreads();
    }
    if (threadIdx.x == 0) bsum[blockIdx.x] = sd[0];
}

__global__ __launch_bounds__(1024) void scan_sums(
    int* __restrict__ bsum, int nb, int* __restrict__ P, int n)
{
    __shared__ int sd[1024];
    const int t = threadIdx.x;
    const int v = (t < nb) ? bsum[t] : 0;
    sd[t] = v; __syncthreads();
    for (int off = 1; off < 1024; off <<= 1) {
        const int add = (t >= off) ? sd[t - off] : 0;
        __syncthreads();
        sd[t] += add;
        __syncthreads();
    }
    if (t < nb) bsum[t] = sd[t] - v;
    if (t == nb - 1) P[n] = sd[t];
}

__global__ __launch_bounds__(256) void scan_write_offsets(
    const int* __restrict__ cnt, int n, const int* __restrict__ bsum, int* __restrict__ P)
{
    __shared__ int sd[256];
    const int t = threadIdx.x;
    const int base = blockIdx.x * SCAN_CHUNK + t * 4;
    int v[4]; int s = 0;
#pragma unroll
    for (int j = 0; j < 4; ++j) { const int idx = base + j; v[j] = (idx < n) ? cnt[idx] : 0; s += v[j]; }
    sd[t] = s; __syncthreads();
    const int own = s;
    for (int off = 1; off < 256; off <<= 1) {
        const int add = (t >= off) ? sd[t - off] : 0;
        __syncthreads();
        sd[t] += add;
        __syncthreads();
    }
    int run = bsum[blockIdx.x] + (sd[t] - own);
#pragma unroll
    for (int j = 0; j < 4; ++j) {
        const int idx = base + j;
        if (idx < n) { P[idx] = run; run += v[j]; }
    }
}

// ---- Persistent-W GEMM: stage W once per block, grid-stride over row tiles.
// W staging traffic: 512 x 64KB = 32MB (was 3125 x 64KB = 200MB).
__global__ __launch_bounds__(256) void gcn_gemm3(
    const float* __restrict__ x, const uint4* __restrict__ wbt,
    const float* __restrict__ bias, unsigned short* __restrict__ hb,
    int M, int ntiles)
{
    __shared__ uint4 smem4[81920 / 16];
    char* smem = (char*)smem4;
    const int tid = threadIdx.x;

    // stage W image once (64KB, linear copy of pre-swizzled image)
    {
        uint4* wl = (uint4*)smem;
#pragma unroll
        for (int it = 0; it < 16; ++it) wl[it * 256 + tid] = wbt[it * 256 + tid];
    }

    const int lane = tid & 63;
    const int wv   = tid >> 6;
    const int wr   = wv >> 1;
    const int wc   = wv & 1;
    const int l15  = lane & 15;
    const int lk   = lane >> 4;

    const int  arow = wr * 16 + l15;
    const char* xrow = smem + 65536 + arow * 512;
    const int  aswz = (arow & 7) << 4;
    const int  bswz = (l15 & 7) << 4;
    const char* brow0 = smem + (size_t)(wc * 64 + l15) * 512;

    // bias per j hoisted out of the tile loop
    float bv[4];
#pragma unroll
    for (int j = 0; j < 4; ++j) bv[j] = bias[wc * 64 + j * 16 + l15];

    const int sr  = tid >> 3;   // staging row 0..31
    const int sks = tid & 7;    // staging k-segment
    char* xbase   = smem + 65536 + sr * 512;
    const int swz = (sr & 7) << 4;

    for (int t = blockIdx.x; t < ntiles; t += gridDim.x) {
        const int row0 = t * BM;

        __syncthreads();   // previous tile's MFMA reads of x buffer done
        {
            const int grow = row0 + sr;
            if (grow < M) {
                const float4* src = reinterpret_cast<const float4*>(x + (size_t)grow * K_IN + sks * 32);
#pragma unroll
                for (int q = 0; q < 8; ++q) {
                    const float4 f = src[q];
                    uint2 v;
                    v.x = (unsigned)f2bf(f.x) | ((unsigned)f2bf(f.y) << 16);
                    v.y = (unsigned)f2bf(f.z) | ((unsigned)f2bf(f.w) << 16);
                    const int kb = sks * 64 + q * 8;
                    *reinterpret_cast<uint2*>(xbase + (((kb & ~15) ^ swz) | (kb & 15))) = v;
                }
            } else {
                const uint2 z = make_uint2(0u, 0u);
#pragma unroll
                for (int q = 0; q < 8; ++q) {
                    const int kb = sks * 64 + q * 8;
                    *reinterpret_cast<uint2*>(xbase + (((kb & ~15) ^ swz) | (kb & 15))) = z;
                }
            }
        }
        __syncthreads();   // x staged (and, on iter 0, W staged)

        f32x4 acc[4] = {};
#pragma unroll
        for (int ks = 0; ks < 8; ++ks) {
            const int kb = ks * 64 + lk * 16;
            const bf16x8 a = *reinterpret_cast<const bf16x8*>(xrow + (kb ^ aswz));
            const int bk = kb ^ bswz;
#pragma unroll
            for (int j = 0; j < 4; ++j) {
                const bf16x8 b = *reinterpret_cast<const bf16x8*>(brow0 + j * (16 * 512) + bk);
                acc[j] = __builtin_amdgcn_mfma_f32_16x16x32_bf16(a, b, acc[j], 0, 0, 0);
            }
        }

#pragma unroll
        for (int j = 0; j < 4; ++j) {
            const int gcol = wc * 64 + j * 16 + l15;
#pragma unroll
            for (int r = 0; r < 4; ++r) {
                const int grow = row0 + wr * 16 + lk * 4 + r;
                if (grow < M)
                    hb[(size_t)grow * N_OUT + gcol] = f2bf(acc[j][r] + bv[j]);
            }
        }
    }
}

// ---- Pass B: place records into private per-(bucket,block) regions
__global__ __launch_bounds__(256) void scatter_records(
    const int* __restrict__ ei, const float* __restrict__ ew, int E, int M, int B,
    const int* __restrict__ P, uint2* __restrict__ rec, int chunk)
{
    __shared__ int cur[1024];
    for (int i = threadIdx.x; i < B; i += 256) cur[i] = P[i * NBLK + blockIdx.x];
    __syncthreads();
    const int beg = blockIdx.x * chunk;
    const int end = min(beg + chunk, E);
    for (int i = beg + threadIdx.x; i < end; i += 256) {
        const int d = ei[i];
        const int s = ei[(size_t)E + i];
        const int pos = atomicAdd(&cur[d >> BSHIFT], 1);
        rec[pos] = make_uint2((unsigned)s | ((unsigned)(d & (BNODES - 1)) << 24),
                              __float_as_uint(ew[i]));
    }
}

// ---- Pass C: per-bucket in-place counting sort by (dstLow, srcWindow) key
__global__ __launch_bounds__(256) void sort_bucket(
    const int* __restrict__ P, uint2* __restrict__ rec,
    int* __restrict__ offsN, int* __restrict__ bflag, int M, int B)
{
    __shared__ uint2 srt[CAP];          // 64 KB staging
    __shared__ int hist[NKEY];          // 8 KB: counts -> exclusive prefix -> cursors
    __shared__ int sd[256];

    const int b   = blockIdx.x;
    const int tid = threadIdx.x;
    const int beg = P[b * NBLK];
    const int end = P[(b + 1) * NBLK];
    const int cnt = end - beg;
    const int node0 = b << BSHIFT;

    for (int i = tid; i < NKEY; i += 256) hist[i] = 0;
    if (tid == 0) bflag[b] = (cnt <= CAP) ? 0 : 1;
    if (tid == 0 && b == B - 1) offsN[M] = end;
    __syncthreads();

    if (cnt > CAP) {
        if (tid < BNODES) {
            const int node = node0 + tid;
            if (node < M) offsN[node] = beg;
        }
        return;
    }

    for (int i = beg + tid; i < end; i += 256) {
        const uint2 r = rec[i];
        srt[i - beg] = r;
        const int key = ((r.x >> 24) << 4) | ((r.x & 0xFFFFFF) >> 13);
        atomicAdd(&hist[key], 1);
    }
    __syncthreads();

    const int base = tid * 8;
    int v[8]; int s = 0;
#pragma unroll
    for (int j = 0; j < 8; ++j) { v[j] = hist[base + j]; s += v[j]; }
    sd[tid] = s; __syncthreads();
    for (int off = 1; off < 256; off <<= 1) {
        const int add = (tid >= off) ? sd[tid - off] : 0;
        __syncthreads();
        sd[tid] += add;
        __syncthreads();
    }
    int run = sd[tid] - s;
#pragma unroll
    for (int j = 0; j < 8; ++j) { hist[base + j] = run; run += v[j]; }
    __syncthreads();

    if (tid < BNODES) {
        const int node = node0 + tid;
        if (node < M) offsN[node] = beg + hist[tid << 4];
    }
    __syncthreads();

    for (int i = tid; i < cnt; i += 256) {
        const uint2 r = srt[i];
        const int key = ((r.x >> 24) << 4) | ((r.x & 0xFFFFFF) >> 13);
        const int pos = atomicAdd(&hist[key], 1);
        rec[beg + pos] = r;
    }
}

// ---- Gather: one wave per node; lane owns feat pair; 16/8-deep batched loads
__global__ __launch_bounds__(256) void gather_kernel(
    const int* __restrict__ offsN, const int* __restrict__ P,
    const int* __restrict__ bflag, const uint2* __restrict__ rec,
    const unsigned short* __restrict__ hb, float* __restrict__ out, int M)
{
    const int n = blockIdx.x * 4 + (threadIdx.x >> 6);
    if (n >= M) return;
    const int lane = threadIdx.x & 63;
    const int b = n >> BSHIFT;
    const unsigned* __restrict__ hb32 = reinterpret_cast<const unsigned*>(hb);

    float ax = 0.f, ay = 0.f;

    if (bflag[b] == 0) {
        const int beg = offsN[n], end = offsN[n + 1];
        int i = beg;
        for (; i + 16 <= end; i += 16) {
            unsigned u[16]; float w[16];
#pragma unroll
            for (int q = 0; q < 16; ++q) {
                const uint2 r = rec[i + q];
                w[q] = __uint_as_float(r.y);
                u[q] = hb32[(size_t)((r.x & 0xFFFFFF) << 6) + lane];
            }
#pragma unroll
            for (int q = 0; q < 16; ++q) {
                ax += w[q] * bf2f((unsigned short)u[q]);
                ay += w[q] * bf2f((unsigned short)(u[q] >> 16));
            }
        }
        for (; i + 8 <= end; i += 8) {
            unsigned u[8]; float w[8];
#pragma unroll
            for (int q = 0; q < 8; ++q) {
                const uint2 r = rec[i + q];
                w[q] = __uint_as_float(r.y);
                u[q] = hb32[(size_t)((r.x & 0xFFFFFF) << 6) + lane];
            }
#pragma unroll
            for (int q = 0; q < 8; ++q) {
                ax += w[q] * bf2f((unsigned short)u[q]);
                ay += w[q] * bf2f((unsigned short)(u[q] >> 16));
            }
        }
        for (; i < end; ++i) {
            const uint2 r = rec[i];
            const float w = __uint_as_float(r.y);
            const unsigned u = hb32[(size_t)((r.x & 0xFFFFFF) << 6) + lane];
            ax += w * bf2f((unsigned short)u);
            ay += w * bf2f((unsigned short)(u >> 16));
        }
    } else {
        const int beg = P[b * NBLK], end = P[(b + 1) * NBLK];
        const unsigned want = (unsigned)(n & (BNODES - 1));
        for (int i = beg; i < end; ++i) {
            const uint2 r = rec[i];
            if ((r.x >> 24) != want) continue;
            const float w = __uint_as_float(r.y);
            const unsigned u = hb32[(size_t)((r.x & 0xFFFFFF) << 6) + lane];
            ax += w * bf2f((unsigned short)u);
            ay += w * bf2f((unsigned short)(u >> 16));
        }
    }

    reinterpret_cast<float2*>(out + (size_t)n * N_OUT)[lane] = make_float2(ax, ay);
}

extern "C" void kernel_launch(void* const* d_in, const int* in_sizes, int n_in,
                              void* d_out, int out_size, void* d_ws, size_t ws_size,
                              hipStream_t stream)
{
    const float* x    = (const float*)d_in[0];
    const int*   ei   = (const int*)d_in[1];
    const float* ew   = (const float*)d_in[2];
    const float* W    = (const float*)d_in[3];
    const float* bias = (const float*)d_in[4];
    float* out = (float*)d_out;

    const int M = in_sizes[0] / K_IN;   // 100000
    const int E = in_sizes[1] / 2;      // 3200000
    const int B = (M + BNODES - 1) >> BSHIFT;          // 782
    const int n = B * NBLK;                             // 400384
    const int nb = (n + SCAN_CHUNK - 1) / SCAN_CHUNK;   // 391
    const int chunk = (E + NBLK - 1) / NBLK;            // 6250
    const int ntiles = (M + BM - 1) / BM;               // 3125

    auto align256 = [](size_t v) { return (v + 255) & ~(size_t)255; };
    const size_t o_hb    = 0;
    const size_t o_hist  = align256(o_hb + (size_t)M * N_OUT * sizeof(unsigned short));
    const size_t o_P     = align256(o_hist + (size_t)n * sizeof(int));
    const size_t o_bsum  = align256(o_P + (size_t)(n + 1) * sizeof(int));
    const size_t o_offsN = align256(o_bsum + (size_t)1024 * sizeof(int));
    const size_t o_bflag = align256(o_offsN + (size_t)(M + 1) * sizeof(int));
    const size_t o_wbt   = align256(o_bflag + (size_t)B * sizeof(int));
    const size_t o_rec   = align256(o_wbt + (size_t)65536);

    unsigned short* hb    = (unsigned short*)((char*)d_ws + o_hb);
    int*            histG = (int*)((char*)d_ws + o_hist);
    int*            P     = (int*)((char*)d_ws + o_P);
    int*            bsum  = (int*)((char*)d_ws + o_bsum);
    int*            offsN = (int*)((char*)d_ws + o_offsN);
    int*            bflag = (int*)((char*)d_ws + o_bflag);
    char*           wbt   = (char*)d_ws + o_wbt;
    uint2*          rec   = (uint2*)((char*)d_ws + o_rec);

    hist_prep<<<NBLK + 16, 256, 0, stream>>>(W, wbt, ei, histG, M, E, B, chunk);
    gcn_gemm3<<<GEMM_BLOCKS, 256, 0, stream>>>(x, (const uint4*)wbt, bias, hb, M, ntiles);
    scan_block_sums<<<nb, 256, 0, stream>>>(histG, n, bsum);
    scan_sums<<<1, 1024, 0, stream>>>(bsum, nb, P, n);
    scan_write_offsets<<<nb, 256, 0, stream>>>(histG, n, bsum, P);
    scatter_records<<<NBLK, 256, 0, stream>>>(ei, ew, E, M, B, P, rec, chunk);
    sort_bucket<<<B, 256, 0, stream>>>(P, rec, offsN, bflag, M, B);
    gather_kernel<<<(M + 3) / 4, 256, 0, stream>>>(offsN, P, bflag, rec, hb, out, M);
}